// Round 7
// baseline (756.066 us; speedup 1.0000x reference)
//
#include <hip/hip_runtime.h>

#define NN 100000
#define DD 128
#define RESC 0.2f
#define EPSL 1e-5f
#define BSH 10
#define NBKT ((NN + 1023) >> BSH)  // 98
#define SLAB 20480                 // bucket slab capacity: mean 16384 + 32 sigma

typedef _Float16 f16;
typedef _Float16 f16x4 __attribute__((ext_vector_type(4)));
typedef _Float16 f16x8 __attribute__((ext_vector_type(8)));
typedef float f32x16 __attribute__((ext_vector_type(16)));

// LDS swizzle: [128][256B] rows, XOR 16B-slot index by (row&15) -> conflict-free MFMA reads
static __device__ __forceinline__ int swzb(int r, int b) {
  return r * 256 + (b ^ ((r & 15) << 4));
}

// ---------------------------------------------------------------- wprep: W transposes to fp16 + slab cursor init
__global__ __launch_bounds__(256) void k_wprep(const float* __restrict__ W1, const float* __restrict__ W2,
                                               f16* __restrict__ Wt1, f16* __restrict__ Wt2,
                                               int* __restrict__ bcur) {
  int i = blockIdx.x * 256 + threadIdx.x;  // 0..32767
  if (i < NBKT) bcur[i] = i * SLAB;
  int w = i >> 14, j = i & 16383;
  int n = j >> 7, k = j & 127;
  const float* W = w ? W2 : W1;
  f16* Wt = w ? Wt2 : Wt1;
  Wt[n * 128 + k] = (f16)W[k * 128 + n];
}

// ---------------------------------------------------------------- histA: dego count + bucket-sort pairs into slabs (one pass)
__global__ __launch_bounds__(256) void k_histA(const int* __restrict__ src, const int* __restrict__ dst,
                                               int* __restrict__ dego, int* __restrict__ bcur,
                                               int2* __restrict__ gpairs, int E) {
  __shared__ int cnt[NBKT], cnt2[NBKT], gofs[NBKT];
  const int t = threadIdx.x;
  if (t < NBKT) { cnt[t] = 0; cnt2[t] = 0; }
  __syncthreads();
  const int base = blockIdx.x * 4096 + t * 16;
  int sv[16], dv[16];
#pragma unroll
  for (int q = 0; q < 4; ++q) {
    int idx = base + q * 4;
    if (idx + 3 < E) {
      *(int4*)(sv + q * 4) = *(const int4*)(src + idx);
      *(int4*)(dv + q * 4) = *(const int4*)(dst + idx);
    } else {
#pragma unroll
      for (int k = 0; k < 4; ++k) {
        sv[q * 4 + k] = (idx + k < E) ? src[idx + k] : 0;
        dv[q * 4 + k] = (idx + k < E) ? dst[idx + k] : -1;
      }
    }
  }
#pragma unroll
  for (int j = 0; j < 16; ++j)
    if (base + j < E) {
      atomicAdd(&dego[sv[j]], 1);
      atomicAdd(&cnt[dv[j] >> BSH], 1);
    }
  __syncthreads();
  if (t < NBKT && cnt[t]) gofs[t] = atomicAdd(&bcur[t], cnt[t]);
  __syncthreads();
#pragma unroll
  for (int j = 0; j < 16; ++j)
    if (base + j < E) {
      int b = dv[j] >> BSH;
      int p = gofs[b] + atomicAdd(&cnt2[b], 1);
      if (p < (b + 1) * SLAB) gpairs[p] = make_int2(sv[j], dv[j]);  // defensive: never OOB
    }
}

// ---------------------------------------------------------------- binB: per-bucket CSR (rowp/rend/rsq_i/rsq_o/colx), slab-relative
__global__ __launch_bounds__(256) void k_binB(const int2* __restrict__ gpairs, const int* __restrict__ bcur,
                                              const int* __restrict__ dego,
                                              int* __restrict__ rowp, int* __restrict__ rend,
                                              float* __restrict__ rsq_i, float* __restrict__ rsq_o,
                                              int* __restrict__ colx) {
  __shared__ int hist[1024];
  __shared__ int part[256];
  const int b = blockIdx.x, t = threadIdx.x;
  const int node0 = b << BSH;
  const int ebase = b * SLAB;
  const int ecnt = min(bcur[b] - ebase, SLAB);  // defensive clamp
  for (int j = t; j < 1024; j += 256) hist[j] = 0;
  __syncthreads();
  for (int i = t; i < ecnt; i += 256)
    atomicAdd(&hist[gpairs[ebase + i].y - node0], 1);
  __syncthreads();
  const int j0 = t * 4;
  const int h0 = hist[j0], h1 = hist[j0 + 1], h2 = hist[j0 + 2], h3 = hist[j0 + 3];
  part[t] = h0 + h1 + h2 + h3;
  __syncthreads();
  for (int off = 1; off < 256; off <<= 1) {
    int add = (t >= off) ? part[t - off] : 0;
    __syncthreads();
    part[t] += add;
    __syncthreads();
  }
  int run = ebase + ((t == 0) ? 0 : part[t - 1]);
  const int pos[4] = {run, run + h0, run + h0 + h1, run + h0 + h1 + h2};
  const int hh[4] = {h0, h1, h2, h3};
#pragma unroll
  for (int k = 0; k < 4; ++k) {
    int node = node0 + j0 + k;
    if (node < NN) {
      rowp[node] = pos[k];
      rend[node] = pos[k] + hh[k];
      rsq_i[node] = rsqrtf((float)max(hh[k], 1));
      rsq_o[node] = rsqrtf((float)max(dego[node], 1));
    }
  }
#pragma unroll
  for (int k = 0; k < 4; ++k) hist[j0 + k] = pos[k];
  __syncthreads();
  for (int i = t; i < ecnt; i += 256) {
    int2 pr = gpairs[ebase + i];
    int p = atomicAdd(&hist[pr.y - node0], 1);
    colx[p] = pr.x;
  }
}

// ---------------------------------------------------------------- shared MFMA tile: out[row0..row0+127][:] = sX @ sW^T (Wt layout)
// v_mfma_f32_32x32x16_f16; C layout col=lane&31, row=(reg&3)+8*(reg>>2)+4*(lane>>5)  [learn_hip m74/m101]
static __device__ __forceinline__ void mfma_store(const char* sX, const char* sW, f16* __restrict__ out,
                                                  int row0, int tid) {
  const int wv = tid >> 6, lane = tid & 63;
  const int am = lane & 31;
  const int kg = lane >> 5;
  f32x16 acc[4];
#pragma unroll
  for (int ct = 0; ct < 4; ++ct)
#pragma unroll
    for (int q = 0; q < 16; ++q) acc[ct][q] = 0.f;

  const int ar = wv * 32 + am;
#pragma unroll
  for (int ks = 0; ks < 8; ++ks) {
    const int kc = ks * 16 + kg * 8;
    f16x8 af = *(const f16x8*)(sX + swzb(ar, kc * 2));
#pragma unroll
    for (int ct = 0; ct < 4; ++ct) {
      f16x8 bf = *(const f16x8*)(sW + swzb(ct * 32 + am, kc * 2));
      acc[ct] = __builtin_amdgcn_mfma_f32_32x32x16_f16(af, bf, acc[ct], 0, 0, 0);
    }
  }
#pragma unroll
  for (int ct = 0; ct < 4; ++ct) {
#pragma unroll
    for (int reg = 0; reg < 16; ++reg) {
      int trow = (reg & 3) + 8 * (reg >> 2) + 4 * kg;
      int grow = row0 + wv * 32 + trow;
      if (grow < NN) out[(size_t)grow * DD + ct * 32 + am] = (f16)acc[ct][reg];
    }
  }
}

// ---------------------------------------------------------------- gemm1: xw = (in_feat * rsq_o) @ W1 (fp32 in, fp16 out)
__global__ __launch_bounds__(256, 2) void k_gemm1(const float* __restrict__ in, const f16* __restrict__ Wt,
                                                  const float* __restrict__ rsq_o, f16* __restrict__ out) {
  extern __shared__ char smem[];
  char* sX = smem;
  char* sW = smem + 32768;
  const int tid = threadIdx.x;
  const int row0 = blockIdx.x * 128;
#pragma unroll
  for (int i = 0; i < 8; ++i) {
    int chunk = i * 256 + tid;
    int r = chunk >> 4, cc = (chunk & 15) * 8;
    *(f16x8*)(sW + swzb(r, cc * 2)) = *(const f16x8*)(Wt + (size_t)r * 128 + cc);
  }
#pragma unroll
  for (int i = 0; i < 8; ++i) {
    int chunk = i * 256 + tid;
    int r = chunk >> 4, cc = (chunk & 15) * 8;
    int grow = row0 + r;
    float4 v0 = {0, 0, 0, 0}, v1 = {0, 0, 0, 0};
    float s = 0.f;
    if (grow < NN) {
      v0 = *(const float4*)(in + (size_t)grow * DD + cc);
      v1 = *(const float4*)(in + (size_t)grow * DD + cc + 4);
      s = rsq_o[grow];
    }
    f16x8 v;
    v[0] = (f16)(v0.x * s); v[1] = (f16)(v0.y * s);
    v[2] = (f16)(v0.z * s); v[3] = (f16)(v0.w * s);
    v[4] = (f16)(v1.x * s); v[5] = (f16)(v1.y * s);
    v[6] = (f16)(v1.z * s); v[7] = (f16)(v1.w * s);
    *(f16x8*)(sX + swzb(r, cc * 2)) = v;
  }
  __syncthreads();
  mfma_store(sX, sW, out, row0, tid);
}

// ---------------------------------------------------------------- conv (fused): h = gather(xw)+b+res; h' = relu(LN(h))*rsq_o -> LDS; xw_out = h' @ W
__global__ __launch_bounds__(256, 2) void k_conv(const f16* __restrict__ xw, const int* __restrict__ colx,
                                                 const int* __restrict__ rowp, const int* __restrict__ rend,
                                                 const float* __restrict__ rsq_i, const float* __restrict__ bias,
                                                 const float* __restrict__ resid, const float* __restrict__ rsq_o,
                                                 const float* __restrict__ g, const float* __restrict__ bb,
                                                 const f16* __restrict__ Wt, f16* __restrict__ out) {
  extern __shared__ char smem[];
  char* sX = smem;
  char* sW = smem + 32768;
  const int tid = threadIdx.x;
  const int row0 = blockIdx.x * 128;
#pragma unroll
  for (int i = 0; i < 8; ++i) {
    int chunk = i * 256 + tid;
    int r = chunk >> 4, cc = (chunk & 15) * 8;
    *(f16x8*)(sW + swzb(r, cc * 2)) = *(const f16x8*)(Wt + (size_t)r * 128 + cc);
  }
  const int wv = tid >> 6, lane = tid & 63;
  const int half = lane >> 5, l32 = lane & 31;
  const float4 bv = *(const float4*)(bias + l32 * 4);
  const float4 gv = *(const float4*)(g + l32 * 4);
  const float4 lv = *(const float4*)(bb + l32 * 4);

  for (int i = 0; i < 32; ++i) {
    const int node = row0 + wv * 32 + i;
    const int r = wv * 32 + i;
    f16x4 o4 = {};
    if (node < NN) {
      const int beg = rowp[node], end = rend[node];
      float4 a0 = {0, 0, 0, 0}, a1 = {0, 0, 0, 0}, a2 = {0, 0, 0, 0}, a3 = {0, 0, 0, 0};
      int e = beg + half;
      for (; e + 6 < end; e += 8) {
        int c0 = colx[e], c1 = colx[e + 2], c2 = colx[e + 4], c3 = colx[e + 6];
        f16x4 v0 = *(const f16x4*)(xw + (size_t)c0 * DD + l32 * 4);
        f16x4 v1 = *(const f16x4*)(xw + (size_t)c1 * DD + l32 * 4);
        f16x4 v2 = *(const f16x4*)(xw + (size_t)c2 * DD + l32 * 4);
        f16x4 v3 = *(const f16x4*)(xw + (size_t)c3 * DD + l32 * 4);
        a0.x += (float)v0[0]; a0.y += (float)v0[1]; a0.z += (float)v0[2]; a0.w += (float)v0[3];
        a1.x += (float)v1[0]; a1.y += (float)v1[1]; a1.z += (float)v1[2]; a1.w += (float)v1[3];
        a2.x += (float)v2[0]; a2.y += (float)v2[1]; a2.z += (float)v2[2]; a2.w += (float)v2[3];
        a3.x += (float)v3[0]; a3.y += (float)v3[1]; a3.z += (float)v3[2]; a3.w += (float)v3[3];
      }
      for (; e < end; e += 2) {
        int c = colx[e];
        f16x4 v = *(const f16x4*)(xw + (size_t)c * DD + l32 * 4);
        a0.x += (float)v[0]; a0.y += (float)v[1]; a0.z += (float)v[2]; a0.w += (float)v[3];
      }
      a0.x += a1.x + a2.x + a3.x;
      a0.y += a1.y + a2.y + a3.y;
      a0.z += a1.z + a2.z + a3.z;
      a0.w += a1.w + a2.w + a3.w;
      a0.x += __shfl_xor(a0.x, 32);
      a0.y += __shfl_xor(a0.y, 32);
      a0.z += __shfl_xor(a0.z, 32);
      a0.w += __shfl_xor(a0.w, 32);

      const float rI = rsq_i[node];
      const float4 rf = *(const float4*)(resid + (size_t)node * DD + l32 * 4);
      float4 o;
      o.x = a0.x * rI + bv.x + RESC * rf.x;
      o.y = a0.y * rI + bv.y + RESC * rf.y;
      o.z = a0.z * rI + bv.z + RESC * rf.z;
      o.w = a0.w * rI + bv.w + RESC * rf.w;

      float s = o.x + o.y + o.z + o.w;
      float q = o.x * o.x + o.y * o.y + o.z * o.z + o.w * o.w;
#pragma unroll
      for (int off = 1; off < 32; off <<= 1) {
        s += __shfl_xor(s, off);
        q += __shfl_xor(q, off);
      }
      float mu = s * (1.f / 128.f);
      float var = q * (1.f / 128.f) - mu * mu;
      float rs = rsqrtf(var + EPSL);
      float sc = rsq_o[node];
      o4[0] = (f16)(fmaxf((o.x - mu) * rs * gv.x + lv.x, 0.f) * sc);
      o4[1] = (f16)(fmaxf((o.y - mu) * rs * gv.y + lv.y, 0.f) * sc);
      o4[2] = (f16)(fmaxf((o.z - mu) * rs * gv.z + lv.z, 0.f) * sc);
      o4[3] = (f16)(fmaxf((o.w - mu) * rs * gv.w + lv.w, 0.f) * sc);
    }
    if (half == 0) *(f16x4*)(sX + swzb(r, l32 * 8)) = o4;
  }
  __syncthreads();
  mfma_store(sX, sW, out, row0, tid);
}

// ---------------------------------------------------------------- final gather: d_out = gather(xw)+b+res (fp32)
__global__ __launch_bounds__(256) void k_gatherF(const f16* __restrict__ xw, const int* __restrict__ colx,
                                                 const int* __restrict__ rowp, const int* __restrict__ rend,
                                                 const float* __restrict__ rsq_i, const float* __restrict__ bias,
                                                 const float* __restrict__ resid, float* __restrict__ out) {
  const int wave = (blockIdx.x * 256 + threadIdx.x) >> 6;
  const int lane = threadIdx.x & 63;
  const int half = lane >> 5;
  const int l32 = lane & 31;
  if (wave >= NN) return;
  const int beg = rowp[wave], end = rend[wave];
  float4 a0 = {0, 0, 0, 0}, a1 = {0, 0, 0, 0}, a2 = {0, 0, 0, 0}, a3 = {0, 0, 0, 0};
  int e = beg + half;
  for (; e + 6 < end; e += 8) {
    int c0 = colx[e], c1 = colx[e + 2], c2 = colx[e + 4], c3 = colx[e + 6];
    f16x4 v0 = *(const f16x4*)(xw + (size_t)c0 * DD + l32 * 4);
    f16x4 v1 = *(const f16x4*)(xw + (size_t)c1 * DD + l32 * 4);
    f16x4 v2 = *(const f16x4*)(xw + (size_t)c2 * DD + l32 * 4);
    f16x4 v3 = *(const f16x4*)(xw + (size_t)c3 * DD + l32 * 4);
    a0.x += (float)v0[0]; a0.y += (float)v0[1]; a0.z += (float)v0[2]; a0.w += (float)v0[3];
    a1.x += (float)v1[0]; a1.y += (float)v1[1]; a1.z += (float)v1[2]; a1.w += (float)v1[3];
    a2.x += (float)v2[0]; a2.y += (float)v2[1]; a2.z += (float)v2[2]; a2.w += (float)v2[3];
    a3.x += (float)v3[0]; a3.y += (float)v3[1]; a3.z += (float)v3[2]; a3.w += (float)v3[3];
  }
  for (; e < end; e += 2) {
    int c = colx[e];
    f16x4 v = *(const f16x4*)(xw + (size_t)c * DD + l32 * 4);
    a0.x += (float)v[0]; a0.y += (float)v[1]; a0.z += (float)v[2]; a0.w += (float)v[3];
  }
  a0.x += a1.x + a2.x + a3.x;
  a0.y += a1.y + a2.y + a3.y;
  a0.z += a1.z + a2.z + a3.z;
  a0.w += a1.w + a2.w + a3.w;
  a0.x += __shfl_xor(a0.x, 32);
  a0.y += __shfl_xor(a0.y, 32);
  a0.z += __shfl_xor(a0.z, 32);
  a0.w += __shfl_xor(a0.w, 32);
  if (half == 0) {
    const float r = rsq_i[wave];
    float4 bv = *(const float4*)(bias + l32 * 4);
    float4 rf = *(const float4*)(resid + (size_t)wave * DD + l32 * 4);
    float4 o;
    o.x = a0.x * r + bv.x + RESC * rf.x;
    o.y = a0.y * r + bv.y + RESC * rf.y;
    o.z = a0.z * r + bv.z + RESC * rf.z;
    o.w = a0.w * r + bv.w + RESC * rf.w;
    *(float4*)(out + (size_t)wave * DD + l32 * 4) = o;
  }
}

// ---------------------------------------------------------------- launcher
extern "C" void kernel_launch(void* const* d_in, const int* in_sizes, int n_in,
                              void* d_out, int out_size, void* d_ws, size_t ws_size,
                              hipStream_t stream) {
  const int* src = (const int*)d_in[0];
  const int* dst = (const int*)d_in[1];
  const float* in_feat = (const float*)d_in[2];
  const float* W1 = (const float*)d_in[3];
  const float* b1 = (const float*)d_in[4];
  const float* W2 = (const float*)d_in[5];
  const float* b2 = (const float*)d_in[6];
  const float* g1 = (const float*)d_in[7];
  const float* lb1 = (const float*)d_in[8];
  const float* g2 = (const float*)d_in[9];
  const float* lb2 = (const float*)d_in[10];
  const int E = in_sizes[0];

  char* p = (char*)d_ws;
  auto alloc = [&](size_t bytes) {
    char* q = p;
    p += (bytes + 255) & ~(size_t)255;
    return q;
  };
  f16*   xw_a  = (f16*)alloc((size_t)NN * DD * 2);   // 25.6 MB (aliases gpairs 16.1 MB)
  f16*   xw_b  = (f16*)alloc((size_t)NN * DD * 2);
  int*   colx  = (int*)alloc((size_t)NBKT * SLAB * 4);  // 8.03 MB, slab layout
  int*   rowp  = (int*)alloc((size_t)NN * 4);
  int*   rend  = (int*)alloc((size_t)NN * 4);
  float* rsq_i = (float*)alloc((size_t)NN * 4);
  float* rsq_o = (float*)alloc((size_t)NN * 4);
  int*   dego  = (int*)alloc((size_t)NN * 4);
  int*   bcur  = (int*)alloc((size_t)NBKT * 4);
  f16*   Wt1   = (f16*)alloc((size_t)DD * DD * 2);
  f16*   Wt2   = (f16*)alloc((size_t)DD * DD * 2);
  if ((size_t)(p - (char*)d_ws) > ws_size) return;
  int2* gpairs = (int2*)xw_a;  // consumed by k_binB before k_gemm1 writes xw_a

  hipMemsetAsync(dego, 0, (size_t)NN * 4, stream);

  const int eb = (E + 4095) / 4096;
  k_wprep<<<128, 256, 0, stream>>>(W1, W2, Wt1, Wt2, bcur);
  k_histA<<<eb, 256, 0, stream>>>(src, dst, dego, bcur, gpairs, E);
  k_binB<<<NBKT, 256, 0, stream>>>(gpairs, bcur, dego, rowp, rend, rsq_i, rsq_o, colx);

  const int gblk = (NN + 127) / 128;
  const int agblk = (NN * 64 + 255) / 256;
  const size_t ldsb = 65536;

  // conv1 GEMM
  k_gemm1<<<gblk, 256, ldsb, stream>>>(in_feat, Wt1, rsq_o, xw_a);
  // conv2 = gather(xw_a)+b1+res -> LN1 -> relu -> @W2
  k_conv<<<gblk, 256, ldsb, stream>>>(xw_a, colx, rowp, rend, rsq_i, b1, in_feat, rsq_o, g1, lb1, Wt2, xw_b);
  // conv3 = gather(xw_b)+b2+res -> LN2 -> relu -> @W2
  k_conv<<<gblk, 256, ldsb, stream>>>(xw_b, colx, rowp, rend, rsq_i, b2, in_feat, rsq_o, g2, lb2, Wt2, xw_a);
  // final: d_out = gather(xw_a)+b2+res (fp32)
  k_gatherF<<<agblk, 256, 0, stream>>>(xw_a, colx, rowp, rend, rsq_i, b2, in_feat, (float*)d_out);
}